// Round 3
// baseline (2841.064 us; speedup 1.0000x reference)
//
#include <hip/hip_runtime.h>
#include <hip/hip_bf16.h>
#include <stdint.h>

// Problem constants (fixed by setup_inputs)
#define NN 16384
#define DD 512
#define NSTRIPE 8     // column stripes, one per XCD (blockIdx % 8)
#define SCOLS 2048    // NN / NSTRIPE
#define BM 128        // block row tile
#define BN 128        // block col tile
#define BK 64         // k chunk staged in LDS
#define NTILES 16     // SCOLS / BN
#define NEG_INF (-3.0e38f)

// LDS layout (R2): UNPADDED [128 rows][64 k] per matrix (global_load_lds needs
// lane-contiguous dest). Granule-XOR swizzle breaks the resulting bank aliasing:
// LDS[row][granule j] holds global 16B-granule (j ^ (row&7)).

typedef unsigned short u16;
typedef __attribute__((ext_vector_type(8))) __bf16 bf16x8;  // MFMA A/B operand (4 VGPRs)
typedef __attribute__((ext_vector_type(8))) short sh8;      // 16B vector
typedef __attribute__((ext_vector_type(4))) float f32x4;    // MFMA C/D

__device__ __forceinline__ u16 f2bf(float f) {  // RNE fp32->bf16
  uint32_t x = __float_as_uint(f);
  x += 0x7fffu + ((x >> 16) & 1u);
  return (u16)(x >> 16);
}
__device__ __forceinline__ float bf2f(u16 u) {
  return __uint_as_float(((uint32_t)u) << 16);
}

// async global->LDS, 16B per lane; lds base must be wave-uniform.
__device__ __forceinline__ void gload_lds16(const u16* g, u16* lds) {
  __builtin_amdgcn_global_load_lds(
      (const __attribute__((address_space(1))) uint32_t*)g,
      (__attribute__((address_space(3))) uint32_t*)lds,
      16, 0, 0);
}

// Insert v into descending-sorted 10-element register array.
__device__ __forceinline__ void ins10(float t[10], float v) {
  #pragma unroll
  for (int j = 0; j < 10; ++j) {
    float hi = fmaxf(t[j], v);
    v = fminf(t[j], v);
    t[j] = hi;
  }
}

__global__ __launch_bounds__(256) void cast_kernel(const float* __restrict__ src,
                                                   u16* __restrict__ dst) {
  int i = (blockIdx.x * 256 + threadIdx.x) * 8;
  const float4* s4 = reinterpret_cast<const float4*>(src + i);
  float4 a = s4[0], b = s4[1];
  sh8 o;
  o[0] = (short)f2bf(a.x); o[1] = (short)f2bf(a.y);
  o[2] = (short)f2bf(a.z); o[3] = (short)f2bf(a.w);
  o[4] = (short)f2bf(b.x); o[5] = (short)f2bf(b.y);
  o[6] = (short)f2bf(b.z); o[7] = (short)f2bf(b.w);
  *reinterpret_cast<sh8*>(dst + i) = o;
}

// diag[r] = <Lb_r, Rb_r> (bf16 inputs, fp32 accumulate) — one wave per row
__global__ __launch_bounds__(256) void diag_kernel(const u16* __restrict__ Lb,
                                                   const u16* __restrict__ Rb,
                                                   float* __restrict__ diag) {
  int r = blockIdx.x * 4 + (threadIdx.x >> 6);
  int lane = threadIdx.x & 63;
  sh8 a = *reinterpret_cast<const sh8*>(Lb + (size_t)r * DD + lane * 8);
  sh8 b = *reinterpret_cast<const sh8*>(Rb + (size_t)r * DD + lane * 8);
  float s = 0.f;
  #pragma unroll
  for (int j = 0; j < 8; ++j) s += bf2f((u16)a[j]) * bf2f((u16)b[j]);
  #pragma unroll
  for (int off = 32; off > 0; off >>= 1) s += __shfl_down(s, off);
  if (lane == 0) diag[r] = s;
}

// Fused GEMM + consumer. Computes rows [rowbase,rowbase+128) x stripe cols of A*B^T
// MODE 0: per-row top-10 within the stripe -> part_out[N][8][10]
// MODE 1: per-row count(2v - p[col] > thr[row]) and max(2v - p[col]) -> cnt/mx parts
template <int MODE>
__global__ __launch_bounds__(256) void csls_gemm(
    const u16* __restrict__ A, const u16* __restrict__ B,
    float* __restrict__ part_out,
    const float* __restrict__ p, const float* __restrict__ thr,
    int* __restrict__ cnt_out, float* __restrict__ mx_out) {
  // 16512 u16 = 33024 B: staging needs 2*8192 u16; MODE-0 C-view needs 64*129 fp32.
  __shared__ u16 smem[16512];
  u16* sA = smem;            // [128][64] unpadded
  u16* sB = smem + 8192;     // [128][64] unpadded

  const int stripe = blockIdx.x & 7;        // XCD-aligned stripe
  const int rowtile = blockIdx.x >> 3;
  const int rowbase = rowtile * BM;
  const int sbase = stripe * SCOLS;

  const int tid = threadIdx.x;
  const int w = tid >> 6;
  const int lane = tid & 63;
  const int quad = lane >> 4;
  const int l16 = lane & 15;
  const int wr = (w >> 1) * 64;  // wave quadrant rows
  const int wc = (w & 1) * 64;   // wave quadrant cols

  // staging-lane decomposition for global_load_lds (8 rows x 8 granules per instr)
  const int lrow8 = lane >> 3;                 // row within 8-row group
  const int sgran = (lane & 7) ^ lrow8;        // swizzled global granule this lane fetches
  const int swz = l16 & 7;                     // fragment-read granule XOR (== row&7)

  float tk[2][10];   // MODE 0: running top-10, phase 0 = row tid>>2, phase 1 = 64 + tid>>2
  int cnt[16];       // MODE 1 state: per (fr,reg) row this lane holds
  float mx[16];
  float thrv[16];
  if constexpr (MODE == 0) {
    #pragma unroll
    for (int ph = 0; ph < 2; ++ph)
      #pragma unroll
      for (int j = 0; j < 10; ++j) tk[ph][j] = NEG_INF;
  } else {
    #pragma unroll
    for (int i = 0; i < 16; ++i) {
      cnt[i] = 0;
      mx[i] = NEG_INF;
      int fr = i >> 2, reg = i & 3;
      thrv[i] = thr[rowbase + wr + 16 * fr + quad * 4 + reg];
    }
  }

  for (int tile = 0; tile < NTILES; ++tile) {
    const int colbase = sbase + tile * BN;
    f32x4 acc[4][4];
    #pragma unroll
    for (int a_ = 0; a_ < 4; ++a_)
      #pragma unroll
      for (int b_ = 0; b_ < 4; ++b_) acc[a_][b_] = (f32x4){0.f, 0.f, 0.f, 0.f};

    float pv[4];
    if constexpr (MODE == 1) {  // prefetch p for this tile's 4 column fragments
      #pragma unroll
      for (int fc = 0; fc < 4; ++fc) pv[fc] = p[colbase + wc + 16 * fc + l16];
    }

    for (int kk = 0; kk < DD; kk += BK) {
      // DMA-stage A chunk [128 rows][64 k] and B chunk [128 cols][64 k].
      // Each instr: 64 lanes x 16B = 8 rows; wave w covers rows [w*32, w*32+32).
      #pragma unroll
      for (int it = 0; it < 4; ++it) {
        int rgrp = w * 32 + it * 8;
        const u16* ga = A + (size_t)(rowbase + rgrp + lrow8) * DD + kk + sgran * 8;
        const u16* gb = B + (size_t)(colbase + rgrp + lrow8) * DD + kk + sgran * 8;
        gload_lds16(ga, sA + rgrp * 64);
        gload_lds16(gb, sB + rgrp * 64);
      }
      __syncthreads();
      #pragma unroll
      for (int ks = 0; ks < BK; ks += 32) {
        const int gq = (ks >> 3) + quad;       // global granule 0..7 this quad reads
        bf16x8 af[4], bfr[4];
        #pragma unroll
        for (int f = 0; f < 4; ++f) {
          int ra = wr + 16 * f + l16;
          int rb = wc + 16 * f + l16;
          af[f]  = *reinterpret_cast<const bf16x8*>(sA + ra * 64 + ((gq ^ swz) << 3));
          bfr[f] = *reinterpret_cast<const bf16x8*>(sB + rb * 64 + ((gq ^ swz) << 3));
        }
        #pragma unroll
        for (int fr = 0; fr < 4; ++fr)
          #pragma unroll
          for (int fc = 0; fc < 4; ++fc)
            acc[fr][fc] = __builtin_amdgcn_mfma_f32_16x16x32_bf16(af[fr], bfr[fc], acc[fr][fc], 0, 0, 0);
      }
      __syncthreads();
    }

    if constexpr (MODE == 0) {
      // Dump C in two 64-row phases into LDS (reusing staging space), scan top-10.
      float* sC = reinterpret_cast<float*>(smem);  // [64][129] = 33024 B
      #pragma unroll
      for (int ph = 0; ph < 2; ++ph) {
        if ((w >> 1) == ph) {
          #pragma unroll
          for (int fr = 0; fr < 4; ++fr)
            #pragma unroll
            for (int fc = 0; fc < 4; ++fc)
              #pragma unroll
              for (int reg = 0; reg < 4; ++reg)
                sC[(16 * fr + quad * 4 + reg) * 129 + wc + 16 * fc + l16] = acc[fr][fc][reg];
        }
        __syncthreads();
        {
          const int rloc = tid >> 2;
          const int cb = tid & 3;   // interleaved cols: bank-conflict-free
          #pragma unroll 4
          for (int i = 0; i < 32; ++i) {
            float v = sC[rloc * 129 + cb + 4 * i];
            if (v > tk[ph][9]) ins10(tk[ph], v);
          }
        }
        __syncthreads();
      }
    } else {
      // Register-direct consume: csls = 2*v - p[col]; count > thr[row]; track max.
      #pragma unroll
      for (int fc = 0; fc < 4; ++fc)
        #pragma unroll
        for (int fr = 0; fr < 4; ++fr)
          #pragma unroll
          for (int reg = 0; reg < 4; ++reg) {
            float t = 2.f * acc[fr][fc][reg] - pv[fc];
            int idx = fr * 4 + reg;
            cnt[idx] += (t > thrv[idx]) ? 1 : 0;
            mx[idx] = fmaxf(mx[idx], t);
          }
    }
  }

  if constexpr (MODE == 0) {
    // Merge 4 partial top-10s per row, write stripe top-10.
    float* sM = reinterpret_cast<float*>(smem);  // [64][40]
    #pragma unroll
    for (int ph = 0; ph < 2; ++ph) {
      __syncthreads();
      #pragma unroll
      for (int j = 0; j < 10; ++j)
        sM[(tid >> 2) * 40 + (tid & 3) * 10 + j] = tk[ph][j];
      __syncthreads();
      if ((tid & 3) == 0) {
        float best[10];
        #pragma unroll
        for (int j = 0; j < 10; ++j) best[j] = NEG_INF;
        for (int j = 0; j < 40; ++j) {
          float v = sM[(tid >> 2) * 40 + j];
          if (v > best[9]) ins10(best, v);
        }
        int rowg = rowbase + ph * 64 + (tid >> 2);
        #pragma unroll
        for (int j = 0; j < 10; ++j)
          part_out[(size_t)rowg * 80 + stripe * 10 + j] = best[j];
      }
      __syncthreads();
    }
  } else {
    // Rows are covered by TWO waves (column halves): reduce within each wave's
    // 16 column-lanes, deposit per-wave partials in LDS, combine pairs per row.
    float* sMx = reinterpret_cast<float*>(smem);        // [4][64] floats
    int*   sCn = reinterpret_cast<int*>(smem) + 256;    // [4][64] ints
    #pragma unroll
    for (int idx = 0; idx < 16; ++idx) {
      int c = cnt[idx];
      float m = mx[idx];
      #pragma unroll
      for (int off = 1; off < 16; off <<= 1) {
        c += __shfl_xor(c, off);
        m = fmaxf(m, __shfl_xor(m, off));
      }
      if (l16 == 0) {
        int fr = idx >> 2, reg = idx & 3;
        int rloc = 16 * fr + quad * 4 + reg;   // row within this wave's 64-row half
        sMx[w * 64 + rloc] = m;
        sCn[w * 64 + rloc] = c;
      }
    }
    __syncthreads();
    if (tid < 128) {
      int half = tid >> 6;       // 0: rows 0-63 (waves 0,1); 1: rows 64-127 (waves 2,3)
      int rloc = tid & 63;
      int c = sCn[(half * 2) * 64 + rloc] + sCn[(half * 2 + 1) * 64 + rloc];
      float m = fmaxf(sMx[(half * 2) * 64 + rloc], sMx[(half * 2 + 1) * 64 + rloc]);
      cnt_out[(rowbase + tid) * 8 + stripe] = c;
      mx_out[(rowbase + tid) * 8 + stripe] = m;
    }
  }
}

// Merge 8 stripes x top-10 -> LR/RL means; p = LR+RL; thr = 2*diag - p
__global__ __launch_bounds__(256) void p_kernel(const float* __restrict__ LRp,
                                                const float* __restrict__ RLp,
                                                const float* __restrict__ diag,
                                                float* __restrict__ pout,
                                                float* __restrict__ throut) {
  int l = blockIdx.x * 256 + threadIdx.x;
  float b1[10], b2[10];
  #pragma unroll
  for (int j = 0; j < 10; ++j) { b1[j] = NEG_INF; b2[j] = NEG_INF; }
  for (int j = 0; j < 80; ++j) {
    float v = LRp[(size_t)l * 80 + j];
    if (v > b1[9]) ins10(b1, v);
    float u = RLp[(size_t)l * 80 + j];
    if (u > b2[9]) ins10(b2, u);
  }
  float s1 = 0.f, s2 = 0.f;
  #pragma unroll
  for (int j = 0; j < 10; ++j) { s1 += b1[j]; s2 += b2[j]; }
  float pv = (s1 + s2) * 0.1f;
  pout[l] = pv;
  throut[l] = 2.f * diag[l] - pv;
}

__global__ __launch_bounds__(256) void final_kernel(const int* __restrict__ cnt,
                                                    const float* __restrict__ mx,
                                                    float* __restrict__ out) {
  int r = blockIdx.x * 256 + threadIdx.x;
  int c = 0;
  float m = NEG_INF;
  #pragma unroll
  for (int s = 0; s < 8; ++s) {
    c += cnt[r * 8 + s];
    m = fmaxf(m, mx[r * 8 + s]);
  }
  out[r] = (float)c;   // rank of the diagonal element (count strictly greater)
  out[NN + r] = m;     // top-1 csls value
}

extern "C" void kernel_launch(void* const* d_in, const int* in_sizes, int n_in,
                              void* d_out, int out_size, void* d_ws, size_t ws_size,
                              hipStream_t stream) {
  const float* L = (const float*)d_in[0];
  const float* R = (const float*)d_in[1];
  char* ws = (char*)d_ws;

  u16* Lb = (u16*)ws;                                  // 16 MB
  u16* Rb = (u16*)(ws + (16ull << 20));                // 16 MB
  size_t off = 32ull << 20;
  float* LRpart = (float*)(ws + off); off += (size_t)NN * 80 * 4;  // 5.24 MB
  float* RLpart = (float*)(ws + off); off += (size_t)NN * 80 * 4;  // 5.24 MB
  float* diag   = (float*)(ws + off); off += (size_t)NN * 4;
  float* pbuf   = (float*)(ws + off); off += (size_t)NN * 4;
  float* thrbuf = (float*)(ws + off); off += (size_t)NN * 4;
  int*   cntp   = (int*)(ws + off);   off += (size_t)NN * 8 * 4;
  float* mxp    = (float*)(ws + off); off += (size_t)NN * 8 * 4;   // total ~43.7 MB

  // 1) fp32 -> bf16 casts
  cast_kernel<<<(NN * DD / (256 * 8)), 256, 0, stream>>>(L, Lb);
  cast_kernel<<<(NN * DD / (256 * 8)), 256, 0, stream>>>(R, Rb);
  // 2) diagonal sim values
  diag_kernel<<<NN / 4, 256, 0, stream>>>(Lb, Rb, diag);
  // 3) LR[l] parts: rows of L*R^T
  csls_gemm<0><<<(NN / BM) * NSTRIPE, 256, 0, stream>>>(Lb, Rb, LRpart, nullptr, nullptr, nullptr, nullptr);
  // 4) RL[r] parts: rows of R*L^T
  csls_gemm<0><<<(NN / BM) * NSTRIPE, 256, 0, stream>>>(Rb, Lb, RLpart, nullptr, nullptr, nullptr, nullptr);
  // 5) merge partials -> p, thr
  p_kernel<<<NN / 256, 256, 0, stream>>>(LRpart, RLpart, diag, pbuf, thrbuf);
  // 6) rank + max pass over rows of R*L^T
  csls_gemm<1><<<(NN / BM) * NSTRIPE, 256, 0, stream>>>(Rb, Lb, nullptr, pbuf, thrbuf, cntp, mxp);
  // 7) reduce stripe parts -> outputs
  final_kernel<<<NN / 256, 256, 0, stream>>>(cntp, mxp, (float*)d_out);
}

// Round 4
// 1926.010 us; speedup vs baseline: 1.4751x; 1.4751x over previous
//
#include <hip/hip_runtime.h>
#include <hip/hip_bf16.h>
#include <stdint.h>

// Problem constants (fixed by setup_inputs)
#define NN 16384
#define DD 512
#define NSTRIPE 8     // column stripes, one per XCD (blockIdx % 8)
#define SCOLS 2048    // NN / NSTRIPE
#define BM 128        // block row tile
#define BN 128        // block col tile
#define BK 64         // k chunk staged in LDS
#define NTILES 16     // SCOLS / BN
#define NEG_INF (-3.0e38f)

// LDS staging (R3): m97-faithful. UNPADDED [128 rows][64 k] per matrix,
// global_load_lds width=16 with STRAIGHT lane->granule mapping (no swizzle —
// R2's XOR-permuted per-lane global addresses regressed 1.55x, theory:
// permutation defeats DMA coalescing). Fragment ds_read_b128 is quad-uniform
// granule — the pattern m97 ran at 874 TF.

typedef unsigned short u16;
typedef __attribute__((ext_vector_type(8))) __bf16 bf16x8;  // MFMA A/B operand (4 VGPRs)
typedef __attribute__((ext_vector_type(8))) short sh8;      // 16B vector
typedef __attribute__((ext_vector_type(4))) float f32x4;    // MFMA C/D

__device__ __forceinline__ u16 f2bf(float f) {  // RNE fp32->bf16
  uint32_t x = __float_as_uint(f);
  x += 0x7fffu + ((x >> 16) & 1u);
  return (u16)(x >> 16);
}
__device__ __forceinline__ float bf2f(u16 u) {
  return __uint_as_float(((uint32_t)u) << 16);
}

// async global->LDS, 16B per lane; lds base must be wave-uniform.
__device__ __forceinline__ void gload_lds16(const u16* g, u16* lds) {
  __builtin_amdgcn_global_load_lds(
      (const __attribute__((address_space(1))) uint32_t*)g,
      (__attribute__((address_space(3))) uint32_t*)lds,
      16, 0, 0);
}

// Insert v into descending-sorted 10-element register array.
__device__ __forceinline__ void ins10(float t[10], float v) {
  #pragma unroll
  for (int j = 0; j < 10; ++j) {
    float hi = fmaxf(t[j], v);
    v = fminf(t[j], v);
    t[j] = hi;
  }
}

__global__ __launch_bounds__(256) void cast_kernel(const float* __restrict__ src,
                                                   u16* __restrict__ dst) {
  int i = (blockIdx.x * 256 + threadIdx.x) * 8;
  const float4* s4 = reinterpret_cast<const float4*>(src + i);
  float4 a = s4[0], b = s4[1];
  sh8 o;
  o[0] = (short)f2bf(a.x); o[1] = (short)f2bf(a.y);
  o[2] = (short)f2bf(a.z); o[3] = (short)f2bf(a.w);
  o[4] = (short)f2bf(b.x); o[5] = (short)f2bf(b.y);
  o[6] = (short)f2bf(b.z); o[7] = (short)f2bf(b.w);
  *reinterpret_cast<sh8*>(dst + i) = o;
}

// diag[r] = <Lb_r, Rb_r> (bf16 inputs, fp32 accumulate) — one wave per row
__global__ __launch_bounds__(256) void diag_kernel(const u16* __restrict__ Lb,
                                                   const u16* __restrict__ Rb,
                                                   float* __restrict__ diag) {
  int r = blockIdx.x * 4 + (threadIdx.x >> 6);
  int lane = threadIdx.x & 63;
  sh8 a = *reinterpret_cast<const sh8*>(Lb + (size_t)r * DD + lane * 8);
  sh8 b = *reinterpret_cast<const sh8*>(Rb + (size_t)r * DD + lane * 8);
  float s = 0.f;
  #pragma unroll
  for (int j = 0; j < 8; ++j) s += bf2f((u16)a[j]) * bf2f((u16)b[j]);
  #pragma unroll
  for (int off = 32; off > 0; off >>= 1) s += __shfl_down(s, off);
  if (lane == 0) diag[r] = s;
}

// Fused GEMM + consumer over G2 = A*B^T (A=R, B=L for this problem).
// MODE 0: per-ROW top-10 (RL) -> row_part[N][8][10]  AND
//         per-COLUMN top-10 partials (LR) -> col_part[rowtile][N][10]
// MODE 1: per-row count(2v - p[col] > thr[row]) and max -> cnt/mx parts
template <int MODE>
__global__ __launch_bounds__(256) void csls_gemm(
    const u16* __restrict__ A, const u16* __restrict__ B,
    float* __restrict__ row_part, float* __restrict__ col_part,
    const float* __restrict__ p, const float* __restrict__ thr,
    int* __restrict__ cnt_out, float* __restrict__ mx_out) {
  // 16512 u16 = 33024 B: staging 2*8192 u16; MODE-0 C-view 64*129 fp32 = 33024 B.
  __shared__ u16 smem[16512];
  u16* sA = smem;            // [128][64] unpadded
  u16* sB = smem + 8192;     // [128][64] unpadded

  const int stripe = blockIdx.x & 7;        // XCD-aligned stripe
  const int rowtile = blockIdx.x >> 3;
  const int rowbase = rowtile * BM;
  const int sbase = stripe * SCOLS;

  const int tid = threadIdx.x;
  const int w = tid >> 6;
  const int lane = tid & 63;
  const int quad = lane >> 4;
  const int l16 = lane & 15;
  const int wr = (w >> 1) * 64;  // wave quadrant rows
  const int wc = (w & 1) * 64;   // wave quadrant cols

  // staging-lane decomposition: 8 rows x 8 granules per DMA instr, natural order
  const int lrow8 = lane >> 3;   // row within 8-row group
  const int gran = lane & 7;     // 16B granule this lane fetches (straight)

  float tk[2][10];   // MODE 0: running row top-10; phase 0 = row tid>>2, phase 1 = +64
  int cnt[16];       // MODE 1 state: per (fr,reg) row this lane holds
  float mx[16];
  float thrv[16];
  if constexpr (MODE == 0) {
    #pragma unroll
    for (int ph = 0; ph < 2; ++ph)
      #pragma unroll
      for (int j = 0; j < 10; ++j) tk[ph][j] = NEG_INF;
  } else {
    #pragma unroll
    for (int i = 0; i < 16; ++i) {
      cnt[i] = 0;
      mx[i] = NEG_INF;
      int fr = i >> 2, reg = i & 3;
      thrv[i] = thr[rowbase + wr + 16 * fr + quad * 4 + reg];
    }
  }

  for (int tile = 0; tile < NTILES; ++tile) {
    const int colbase = sbase + tile * BN;
    f32x4 acc[4][4];
    #pragma unroll
    for (int a_ = 0; a_ < 4; ++a_)
      #pragma unroll
      for (int b_ = 0; b_ < 4; ++b_) acc[a_][b_] = (f32x4){0.f, 0.f, 0.f, 0.f};

    float pv[4];
    if constexpr (MODE == 1) {  // prefetch p for this tile's 4 column fragments
      #pragma unroll
      for (int fc = 0; fc < 4; ++fc) pv[fc] = p[colbase + wc + 16 * fc + l16];
    }

    for (int kk = 0; kk < DD; kk += BK) {
      // DMA-stage A chunk [128][64] and B chunk [128][64]; wave w covers rows
      // [w*32, w*32+32) of each; lane-sequential (coalesced) global addresses.
      #pragma unroll
      for (int it = 0; it < 4; ++it) {
        int rgrp = w * 32 + it * 8;
        const u16* ga = A + (size_t)(rowbase + rgrp + lrow8) * DD + kk + gran * 8;
        const u16* gb = B + (size_t)(colbase + rgrp + lrow8) * DD + kk + gran * 8;
        gload_lds16(ga, sA + rgrp * 64);
        gload_lds16(gb, sB + rgrp * 64);
      }
      __syncthreads();
      #pragma unroll
      for (int ks = 0; ks < BK; ks += 32) {
        bf16x8 af[4], bfr[4];
        #pragma unroll
        for (int f = 0; f < 4; ++f) {
          int ra = wr + 16 * f + l16;
          int rb = wc + 16 * f + l16;
          af[f]  = *reinterpret_cast<const bf16x8*>(sA + ra * 64 + ks + quad * 8);
          bfr[f] = *reinterpret_cast<const bf16x8*>(sB + rb * 64 + ks + quad * 8);
        }
        #pragma unroll
        for (int fr = 0; fr < 4; ++fr)
          #pragma unroll
          for (int fc = 0; fc < 4; ++fc)
            acc[fr][fc] = __builtin_amdgcn_mfma_f32_16x16x32_bf16(af[fr], bfr[fc], acc[fr][fc], 0, 0, 0);
      }
      __syncthreads();
    }

    if constexpr (MODE == 0) {
      // Dump C in two 64-row phases into LDS; scan rows (RL) and columns (LR).
      float ck[10];  // this tile's per-column top-10 (col = tid&127, half tid>>7)
      #pragma unroll
      for (int j = 0; j < 10; ++j) ck[j] = NEG_INF;
      float* sC = reinterpret_cast<float*>(smem);  // [64][129]
      #pragma unroll
      for (int ph = 0; ph < 2; ++ph) {
        if ((w >> 1) == ph) {
          #pragma unroll
          for (int fr = 0; fr < 4; ++fr)
            #pragma unroll
            for (int fc = 0; fc < 4; ++fc)
              #pragma unroll
              for (int reg = 0; reg < 4; ++reg)
                sC[(16 * fr + quad * 4 + reg) * 129 + wc + 16 * fc + l16] = acc[fr][fc][reg];
        }
        __syncthreads();
        {  // row scan: 4 threads per row, interleaved cols (conflict-free)
          const int rloc = tid >> 2;
          const int cb = tid & 3;
          #pragma unroll 4
          for (int i = 0; i < 32; ++i) {
            float v = sC[rloc * 129 + cb + 4 * i];
            if (v > tk[ph][9]) ins10(tk[ph], v);
          }
        }
        {  // col scan: 2 threads per col (row halves), lanes on consecutive cols
          const int c = tid & 127;
          const int h = tid >> 7;
          #pragma unroll 4
          for (int i = 0; i < 32; ++i) {
            float v = sC[(h * 32 + i) * 129 + c];
            if (v > ck[9]) ins10(ck, v);
          }
        }
        __syncthreads();
      }
      // merge the 2 half-partials per column, write this (rowtile, col) partial
      float* sP = reinterpret_cast<float*>(smem);  // [128][21]
      #pragma unroll
      for (int j = 0; j < 10; ++j)
        sP[(tid & 127) * 21 + (tid >> 7) * 10 + j] = ck[j];
      __syncthreads();
      if (tid < 128) {
        float best[10];
        #pragma unroll
        for (int j = 0; j < 10; ++j) best[j] = NEG_INF;
        for (int j = 0; j < 20; ++j) {
          float v = sP[tid * 21 + j];
          if (v > best[9]) ins10(best, v);
        }
        size_t base = ((size_t)rowtile * NN + colbase + tid) * 10;
        #pragma unroll
        for (int j = 0; j < 10; ++j) col_part[base + j] = best[j];
      }
      __syncthreads();
    } else {
      // Register-direct consume: csls = 2*v - p[col]; count > thr[row]; track max.
      #pragma unroll
      for (int fc = 0; fc < 4; ++fc)
        #pragma unroll
        for (int fr = 0; fr < 4; ++fr)
          #pragma unroll
          for (int reg = 0; reg < 4; ++reg) {
            float t = 2.f * acc[fr][fc][reg] - pv[fc];
            int idx = fr * 4 + reg;
            cnt[idx] += (t > thrv[idx]) ? 1 : 0;
            mx[idx] = fmaxf(mx[idx], t);
          }
    }
  }

  if constexpr (MODE == 0) {
    // Merge 4 partial row top-10s per row, write stripe top-10 (RL partials).
    float* sM = reinterpret_cast<float*>(smem);  // [64][40]
    #pragma unroll
    for (int ph = 0; ph < 2; ++ph) {
      __syncthreads();
      #pragma unroll
      for (int j = 0; j < 10; ++j)
        sM[(tid >> 2) * 40 + (tid & 3) * 10 + j] = tk[ph][j];
      __syncthreads();
      if ((tid & 3) == 0) {
        float best[10];
        #pragma unroll
        for (int j = 0; j < 10; ++j) best[j] = NEG_INF;
        for (int j = 0; j < 40; ++j) {
          float v = sM[(tid >> 2) * 40 + j];
          if (v > best[9]) ins10(best, v);
        }
        int rowg = rowbase + ph * 64 + (tid >> 2);
        #pragma unroll
        for (int j = 0; j < 10; ++j)
          row_part[(size_t)rowg * 80 + stripe * 10 + j] = best[j];
      }
      __syncthreads();
    }
  } else {
    // Rows covered by TWO waves (column halves): shuffle-reduce, LDS-combine.
    float* sMx = reinterpret_cast<float*>(smem);        // [4][64] floats
    int*   sCn = reinterpret_cast<int*>(smem) + 256;    // [4][64] ints
    #pragma unroll
    for (int idx = 0; idx < 16; ++idx) {
      int c = cnt[idx];
      float m = mx[idx];
      #pragma unroll
      for (int off = 1; off < 16; off <<= 1) {
        c += __shfl_xor(c, off);
        m = fmaxf(m, __shfl_xor(m, off));
      }
      if (l16 == 0) {
        int fr = idx >> 2, reg = idx & 3;
        int rloc = 16 * fr + quad * 4 + reg;
        sMx[w * 64 + rloc] = m;
        sCn[w * 64 + rloc] = c;
      }
    }
    __syncthreads();
    if (tid < 128) {
      int half = tid >> 6;
      int rloc = tid & 63;
      int c = sCn[(half * 2) * 64 + rloc] + sCn[(half * 2 + 1) * 64 + rloc];
      float m = fmaxf(sMx[(half * 2) * 64 + rloc], sMx[(half * 2 + 1) * 64 + rloc]);
      cnt_out[(rowbase + tid) * 8 + stripe] = c;
      mx_out[(rowbase + tid) * 8 + stripe] = m;
    }
  }
}

// Per entity l: RL[l] = mean top-10 of row_part[l][80]; LR[l] = mean top-10 of
// col_part[t][l][10] over t=0..127. p = LR+RL; thr = 2*diag - p.
__global__ __launch_bounds__(256) void p_kernel(const float* __restrict__ RLp,
                                                const float* __restrict__ colp,
                                                const float* __restrict__ diag,
                                                float* __restrict__ pout,
                                                float* __restrict__ throut) {
  int l = blockIdx.x * 256 + threadIdx.x;
  float b1[10], b2[10];
  #pragma unroll
  for (int j = 0; j < 10; ++j) { b1[j] = NEG_INF; b2[j] = NEG_INF; }
  for (int s = 0; s < 8; ++s) {
    for (int j = 0; j < 10; ++j) {   // stripe partials sorted desc -> early break
      float v = RLp[(size_t)l * 80 + s * 10 + j];
      if (v > b1[9]) ins10(b1, v); else break;
    }
  }
  for (int t = 0; t < 128; ++t) {
    for (int j = 0; j < 10; ++j) {   // rowtile partials sorted desc -> early break
      float v = colp[((size_t)t * NN + l) * 10 + j];
      if (v > b2[9]) ins10(b2, v); else break;
    }
  }
  float s1 = 0.f, s2 = 0.f;
  #pragma unroll
  for (int j = 0; j < 10; ++j) { s1 += b1[j]; s2 += b2[j]; }
  float pv = (s1 + s2) * 0.1f;
  pout[l] = pv;
  throut[l] = 2.f * diag[l] - pv;
}

__global__ __launch_bounds__(256) void final_kernel(const int* __restrict__ cnt,
                                                    const float* __restrict__ mx,
                                                    float* __restrict__ out) {
  int r = blockIdx.x * 256 + threadIdx.x;
  int c = 0;
  float m = NEG_INF;
  #pragma unroll
  for (int s = 0; s < 8; ++s) {
    c += cnt[r * 8 + s];
    m = fmaxf(m, mx[r * 8 + s]);
  }
  out[r] = (float)c;   // rank of the diagonal element (count strictly greater)
  out[NN + r] = m;     // top-1 csls value
}

extern "C" void kernel_launch(void* const* d_in, const int* in_sizes, int n_in,
                              void* d_out, int out_size, void* d_ws, size_t ws_size,
                              hipStream_t stream) {
  const float* L = (const float*)d_in[0];
  const float* R = (const float*)d_in[1];
  char* ws = (char*)d_ws;

  u16* Lb = (u16*)ws;                                  // 16 MB
  u16* Rb = (u16*)(ws + (16ull << 20));                // 16 MB
  size_t off = 32ull << 20;
  float* colpart = (float*)(ws + off); off += (size_t)NN * 128 * 10 * 4;  // 80 MB
  float* RLpart  = (float*)(ws + off); off += (size_t)NN * 80 * 4;        // 5.24 MB
  float* diag    = (float*)(ws + off); off += (size_t)NN * 4;
  float* pbuf    = (float*)(ws + off); off += (size_t)NN * 4;
  float* thrbuf  = (float*)(ws + off); off += (size_t)NN * 4;
  int*   cntp    = (int*)(ws + off);   off += (size_t)NN * 8 * 4;
  float* mxp     = (float*)(ws + off); off += (size_t)NN * 8 * 4;  // total ~119 MB

  // 1) fp32 -> bf16 casts
  cast_kernel<<<(NN * DD / (256 * 8)), 256, 0, stream>>>(L, Lb);
  cast_kernel<<<(NN * DD / (256 * 8)), 256, 0, stream>>>(R, Rb);
  // 2) diagonal sim values
  diag_kernel<<<NN / 4, 256, 0, stream>>>(Lb, Rb, diag);
  // 3) single fused pass over G2 = R*L^T: row top-10 (RL) + col top-10 partials (LR)
  csls_gemm<0><<<(NN / BM) * NSTRIPE, 256, 0, stream>>>(Rb, Lb, RLpart, colpart,
                                                        nullptr, nullptr, nullptr, nullptr);
  // 4) merge partials -> p, thr
  p_kernel<<<NN / 256, 256, 0, stream>>>(RLpart, colpart, diag, pbuf, thrbuf);
  // 5) rank + max pass over rows of G2
  csls_gemm<1><<<(NN / BM) * NSTRIPE, 256, 0, stream>>>(Rb, Lb, nullptr, nullptr,
                                                        pbuf, thrbuf, cntp, mxp);
  // 6) reduce stripe parts -> outputs
  final_kernel<<<NN / 256, 256, 0, stream>>>(cntp, mxp, (float*)d_out);
}

// Round 6
// 1845.166 us; speedup vs baseline: 1.5397x; 1.0438x over previous
//
#include <hip/hip_runtime.h>
#include <hip/hip_bf16.h>
#include <stdint.h>

// Problem constants (fixed by setup_inputs)
#define NN 16384
#define DD 512
#define NSTRIPE 8     // column stripes, one per XCD (blockIdx % 8)
#define SCOLS 2048    // NN / NSTRIPE
#define BM 128        // block row tile
#define BN 128        // block col tile
#define BK 64         // k chunk staged in LDS
#define NTILES 16     // SCOLS / BN
#define NEG_INF (-3.0e38f)

// R5 retreat: full-S materialization (575 MB) crashed -> ws_size < that.
// Back to R4 structure (proven ~119 MB ws), with a rebuilt MODE-0 epilogue:
// single fp16 C-dump [128][136] + conflict-free row/col scans, 4 barriers/tile.

typedef unsigned short u16;
typedef _Float16 f16;
typedef __attribute__((ext_vector_type(8))) __bf16 bf16x8;   // MFMA A/B operand
typedef __attribute__((ext_vector_type(8))) short sh8;       // 16B vector
typedef __attribute__((ext_vector_type(8))) _Float16 f16x8;  // 16B of fp16
typedef __attribute__((ext_vector_type(4))) float f32x4;     // MFMA C/D

__device__ __forceinline__ u16 f2bf(float f) {  // RNE fp32->bf16
  uint32_t x = __float_as_uint(f);
  x += 0x7fffu + ((x >> 16) & 1u);
  return (u16)(x >> 16);
}
__device__ __forceinline__ float bf2f(u16 u) {
  return __uint_as_float(((uint32_t)u) << 16);
}

// async global->LDS, 16B per lane; lds base wave-uniform.
__device__ __forceinline__ void gload_lds16(const u16* g, u16* lds) {
  __builtin_amdgcn_global_load_lds(
      (const __attribute__((address_space(1))) uint32_t*)g,
      (__attribute__((address_space(3))) uint32_t*)lds,
      16, 0, 0);
}

// Insert v into descending-sorted 10-element register array.
__device__ __forceinline__ void ins10(float t[10], float v) {
  #pragma unroll
  for (int j = 0; j < 10; ++j) {
    float hi = fmaxf(t[j], v);
    v = fminf(t[j], v);
    t[j] = hi;
  }
}

__global__ __launch_bounds__(256) void cast_kernel(const float* __restrict__ src,
                                                   u16* __restrict__ dst) {
  int i = (blockIdx.x * 256 + threadIdx.x) * 8;
  const float4* s4 = reinterpret_cast<const float4*>(src + i);
  float4 a = s4[0], b = s4[1];
  sh8 o;
  o[0] = (short)f2bf(a.x); o[1] = (short)f2bf(a.y);
  o[2] = (short)f2bf(a.z); o[3] = (short)f2bf(a.w);
  o[4] = (short)f2bf(b.x); o[5] = (short)f2bf(b.y);
  o[6] = (short)f2bf(b.z); o[7] = (short)f2bf(b.w);
  *reinterpret_cast<sh8*>(dst + i) = o;
}

// diag[r] = <Lb_r, Rb_r> (bf16 inputs, fp32 accumulate) — one wave per row
__global__ __launch_bounds__(256) void diag_kernel(const u16* __restrict__ Lb,
                                                   const u16* __restrict__ Rb,
                                                   float* __restrict__ diag) {
  int r = blockIdx.x * 4 + (threadIdx.x >> 6);
  int lane = threadIdx.x & 63;
  sh8 a = *reinterpret_cast<const sh8*>(Lb + (size_t)r * DD + lane * 8);
  sh8 b = *reinterpret_cast<const sh8*>(Rb + (size_t)r * DD + lane * 8);
  float s = 0.f;
  #pragma unroll
  for (int j = 0; j < 8; ++j) s += bf2f((u16)a[j]) * bf2f((u16)b[j]);
  #pragma unroll
  for (int off = 32; off > 0; off >>= 1) s += __shfl_down(s, off);
  if (lane == 0) diag[r] = s;
}

// Fused GEMM + consumer over G2 = A*B^T (A=R, B=L).
// MODE 0: per-ROW top-10 (RL) -> row_part[N][8][10]  AND
//         per-COLUMN top-10 partials (LR) -> col_part[rowtile][N][10]
// MODE 1: per-row count(2v - p[col] > thr[row]) and max -> cnt/mx parts
template <int MODE>
__global__ __launch_bounds__(256) void csls_gemm(
    const u16* __restrict__ A, const u16* __restrict__ B,
    float* __restrict__ row_part, float* __restrict__ col_part,
    const float* __restrict__ p, const float* __restrict__ thr,
    int* __restrict__ cnt_out, float* __restrict__ mx_out) {
  // 17408 u16 = 34816 B: staging 2*8192 u16; MODE-0 fp16 C-view 128*136 f16.
  __shared__ __align__(16) u16 smem[17408];
  u16* sA = smem;            // [128][64] unpadded
  u16* sB = smem + 8192;     // [128][64] unpadded

  const int stripe = blockIdx.x & 7;        // XCD-aligned stripe
  const int rowtile = blockIdx.x >> 3;
  const int rowbase = rowtile * BM;
  const int sbase = stripe * SCOLS;

  const int tid = threadIdx.x;
  const int w = tid >> 6;
  const int lane = tid & 63;
  const int quad = lane >> 4;
  const int l16 = lane & 15;
  const int wr = (w >> 1) * 64;  // wave quadrant rows
  const int wc = (w & 1) * 64;   // wave quadrant cols

  // staging-lane decomposition: 8 rows x 8 granules per DMA instr, straight order
  const int lrow8 = lane >> 3;   // row within 8-row group
  const int gran = lane & 7;     // 16B granule this lane fetches

  float tk[10];      // MODE 0: running top-10 of (row = tid>>1, col-half = tid&1)
  int cnt[16];       // MODE 1: per (fr,reg) row this lane holds
  float mx[16];
  float thrv[16];
  if constexpr (MODE == 0) {
    #pragma unroll
    for (int j = 0; j < 10; ++j) tk[j] = NEG_INF;
  } else {
    #pragma unroll
    for (int i = 0; i < 16; ++i) {
      cnt[i] = 0;
      mx[i] = NEG_INF;
      int fr = i >> 2, reg = i & 3;
      thrv[i] = thr[rowbase + wr + 16 * fr + quad * 4 + reg];
    }
  }

  for (int tile = 0; tile < NTILES; ++tile) {
    const int colbase = sbase + tile * BN;
    f32x4 acc[4][4];
    #pragma unroll
    for (int a_ = 0; a_ < 4; ++a_)
      #pragma unroll
      for (int b_ = 0; b_ < 4; ++b_) acc[a_][b_] = (f32x4){0.f, 0.f, 0.f, 0.f};

    float pv[4];
    if constexpr (MODE == 1) {
      #pragma unroll
      for (int fc = 0; fc < 4; ++fc) pv[fc] = p[colbase + wc + 16 * fc + l16];
    }

    for (int kk = 0; kk < DD; kk += BK) {
      #pragma unroll
      for (int it = 0; it < 4; ++it) {
        int rgrp = w * 32 + it * 8;
        gload_lds16(A + (size_t)(rowbase + rgrp + lrow8) * DD + kk + gran * 8, sA + rgrp * 64);
        gload_lds16(B + (size_t)(colbase + rgrp + lrow8) * DD + kk + gran * 8, sB + rgrp * 64);
      }
      __syncthreads();
      #pragma unroll
      for (int ks = 0; ks < BK; ks += 32) {
        bf16x8 af[4], bfr[4];
        #pragma unroll
        for (int f = 0; f < 4; ++f) {
          int ra = wr + 16 * f + l16;
          int rb = wc + 16 * f + l16;
          af[f]  = *reinterpret_cast<const bf16x8*>(sA + ra * 64 + ks + quad * 8);
          bfr[f] = *reinterpret_cast<const bf16x8*>(sB + rb * 64 + ks + quad * 8);
        }
        #pragma unroll
        for (int fr = 0; fr < 4; ++fr)
          #pragma unroll
          for (int fc = 0; fc < 4; ++fc)
            acc[fr][fc] = __builtin_amdgcn_mfma_f32_16x16x32_bf16(af[fr], bfr[fc], acc[fr][fc], 0, 0, 0);
      }
      __syncthreads();
    }

    if constexpr (MODE == 0) {
      // --- R5 epilogue: single fp16 dump [128][136], conflict-free scans ---
      f16* hC = reinterpret_cast<f16*>(smem);
      #pragma unroll
      for (int fr = 0; fr < 4; ++fr)
        #pragma unroll
        for (int fc = 0; fc < 4; ++fc)
          #pragma unroll
          for (int reg = 0; reg < 4; ++reg)
            hC[(wr + 16 * fr + quad * 4 + reg) * 136 + wc + 16 * fc + l16] =
                (f16)acc[fr][fc][reg];
      __syncthreads();
      // row scan: thread owns (row = tid>>1, col-half = tid&1); 8x f16x8 reads.
      {
        const int row = tid >> 1, hf = tid & 1;
        const f16* q = hC + row * 136 + hf * 64;
        #pragma unroll
        for (int c8 = 0; c8 < 8; ++c8) {
          f16x8 v8 = *reinterpret_cast<const f16x8*>(q + c8 * 8);
          #pragma unroll
          for (int j = 0; j < 8; ++j) {
            float v = (float)v8[j];
            if (v > tk[9]) ins10(tk, v);
          }
        }
      }
      // col scan: thread owns (col = tid&127, row-half = tid>>7); 64 b16 reads.
      float ck[10];
      #pragma unroll
      for (int j = 0; j < 10; ++j) ck[j] = NEG_INF;
      {
        const int c = tid & 127, rh = tid >> 7;
        #pragma unroll 8
        for (int i = 0; i < 64; ++i) {
          float v = (float)hC[(rh * 64 + i) * 136 + c];
          if (v > ck[9]) ins10(ck, v);
        }
      }
      __syncthreads();
      // flush this tile's column partials: sP[col][half][10], stride 21 (pad)
      float* sP = reinterpret_cast<float*>(smem);  // 128*21*4 = 10752 B
      {
        const int c = tid & 127, rh = tid >> 7;
        #pragma unroll
        for (int j = 0; j < 10; ++j) sP[c * 21 + rh * 10 + j] = ck[j];
      }
      __syncthreads();
      if (tid < 128) {
        float best[10];
        #pragma unroll
        for (int j = 0; j < 10; ++j) best[j] = NEG_INF;
        #pragma unroll
        for (int j = 0; j < 20; ++j) {
          float v = sP[tid * 21 + j];
          if (v > best[9]) ins10(best, v);
        }
        size_t base = ((size_t)rowtile * NN + colbase + tid) * 10;
        #pragma unroll
        for (int j = 0; j < 10; ++j) col_part[base + j] = best[j];
      }
      __syncthreads();
    } else {
      // Register-direct consume: csls = 2*v - p[col]; count > thr[row]; max.
      #pragma unroll
      for (int fc = 0; fc < 4; ++fc)
        #pragma unroll
        for (int fr = 0; fr < 4; ++fr)
          #pragma unroll
          for (int reg = 0; reg < 4; ++reg) {
            float t = 2.f * acc[fr][fc][reg] - pv[fc];
            int idx = fr * 4 + reg;
            cnt[idx] += (t > thrv[idx]) ? 1 : 0;
            mx[idx] = fmaxf(mx[idx], t);
          }
    }
  }

  if constexpr (MODE == 0) {
    // Merge the 2 col-half partials per row (hoisted out of the tile loop).
    float* sM = reinterpret_cast<float*>(smem);  // [128][21]
    #pragma unroll
    for (int j = 0; j < 10; ++j)
      sM[(tid >> 1) * 21 + (tid & 1) * 10 + j] = tk[j];
    __syncthreads();
    if (tid < 128) {
      float best[10];
      #pragma unroll
      for (int j = 0; j < 10; ++j) best[j] = NEG_INF;
      #pragma unroll
      for (int j = 0; j < 20; ++j) {
        float v = sM[tid * 21 + j];
        if (v > best[9]) ins10(best, v);
      }
      #pragma unroll
      for (int j = 0; j < 10; ++j)
        row_part[(size_t)(rowbase + tid) * 80 + stripe * 10 + j] = best[j];
    }
  } else {
    // Rows covered by TWO waves (column halves): shuffle-reduce, LDS-combine.
    float* sMx = reinterpret_cast<float*>(smem);        // [4][64] floats
    int*   sCn = reinterpret_cast<int*>(smem) + 256;    // [4][64] ints
    #pragma unroll
    for (int idx = 0; idx < 16; ++idx) {
      int c = cnt[idx];
      float m = mx[idx];
      #pragma unroll
      for (int off = 1; off < 16; off <<= 1) {
        c += __shfl_xor(c, off);
        m = fmaxf(m, __shfl_xor(m, off));
      }
      if (l16 == 0) {
        int fr = idx >> 2, reg = idx & 3;
        int rloc = 16 * fr + quad * 4 + reg;
        sMx[w * 64 + rloc] = m;
        sCn[w * 64 + rloc] = c;
      }
    }
    __syncthreads();
    if (tid < 128) {
      int half = tid >> 6;
      int rloc = tid & 63;
      int c = sCn[(half * 2) * 64 + rloc] + sCn[(half * 2 + 1) * 64 + rloc];
      float m = fmaxf(sMx[(half * 2) * 64 + rloc], sMx[(half * 2 + 1) * 64 + rloc]);
      cnt_out[(rowbase + tid) * 8 + stripe] = c;
      mx_out[(rowbase + tid) * 8 + stripe] = m;
    }
  }
}

// Per entity l: RL[l] = mean top-10 of row_part[l][80]; LR[l] = mean top-10 of
// col_part[t][l][10] over t=0..127. p = LR+RL; thr = 2*diag - p.
__global__ __launch_bounds__(256) void p_kernel(const float* __restrict__ RLp,
                                                const float* __restrict__ colp,
                                                const float* __restrict__ diag,
                                                float* __restrict__ pout,
                                                float* __restrict__ throut) {
  int l = blockIdx.x * 256 + threadIdx.x;
  float b1[10], b2[10];
  #pragma unroll
  for (int j = 0; j < 10; ++j) { b1[j] = NEG_INF; b2[j] = NEG_INF; }
  for (int s = 0; s < 8; ++s) {
    for (int j = 0; j < 10; ++j) {   // stripe partials sorted desc -> early break
      float v = RLp[(size_t)l * 80 + s * 10 + j];
      if (v > b1[9]) ins10(b1, v); else break;
    }
  }
  for (int t = 0; t < 128; ++t) {
    for (int j = 0; j < 10; ++j) {   // rowtile partials sorted desc -> early break
      float v = colp[((size_t)t * NN + l) * 10 + j];
      if (v > b2[9]) ins10(b2, v); else break;
    }
  }
  float s1 = 0.f, s2 = 0.f;
  #pragma unroll
  for (int j = 0; j < 10; ++j) { s1 += b1[j]; s2 += b2[j]; }
  float pv = (s1 + s2) * 0.1f;
  pout[l] = pv;
  throut[l] = 2.f * diag[l] - pv;
}

__global__ __launch_bounds__(256) void final_kernel(const int* __restrict__ cnt,
                                                    const float* __restrict__ mx,
                                                    float* __restrict__ out) {
  int r = blockIdx.x * 256 + threadIdx.x;
  int c = 0;
  float m = NEG_INF;
  #pragma unroll
  for (int s = 0; s < 8; ++s) {
    c += cnt[r * 8 + s];
    m = fmaxf(m, mx[r * 8 + s]);
  }
  out[r] = (float)c;   // rank of the diagonal element (count strictly greater)
  out[NN + r] = m;     // top-1 csls value
}

extern "C" void kernel_launch(void* const* d_in, const int* in_sizes, int n_in,
                              void* d_out, int out_size, void* d_ws, size_t ws_size,
                              hipStream_t stream) {
  const float* L = (const float*)d_in[0];
  const float* R = (const float*)d_in[1];
  char* ws = (char*)d_ws;

  u16* Lb = (u16*)ws;                                   // 16 MB
  u16* Rb = (u16*)(ws + (16ull << 20));                 // 16 MB
  size_t off = 32ull << 20;
  float* colpart = (float*)(ws + off); off += (size_t)NN * 128 * 10 * 4;  // 80 MB
  float* RLpart  = (float*)(ws + off); off += (size_t)NN * 80 * 4;        // 5.24 MB
  float* diag    = (float*)(ws + off); off += (size_t)NN * 4;
  float* pbuf    = (float*)(ws + off); off += (size_t)NN * 4;
  float* thrbuf  = (float*)(ws + off); off += (size_t)NN * 4;
  int*   cntp    = (int*)(ws + off);   off += (size_t)NN * 8 * 4;
  float* mxp     = (float*)(ws + off); off += (size_t)NN * 8 * 4;  // ~119 MB total

  // 1) fp32 -> bf16 casts
  cast_kernel<<<(NN * DD / (256 * 8)), 256, 0, stream>>>(L, Lb);
  cast_kernel<<<(NN * DD / (256 * 8)), 256, 0, stream>>>(R, Rb);
  // 2) diagonal sim values
  diag_kernel<<<NN / 4, 256, 0, stream>>>(Lb, Rb, diag);
  // 3) fused pass over G2 = R*L^T: row top-10 (RL) + col top-10 partials (LR)
  csls_gemm<0><<<(NN / BM) * NSTRIPE, 256, 0, stream>>>(Rb, Lb, RLpart, colpart,
                                                        nullptr, nullptr, nullptr, nullptr);
  // 4) merge partials -> p, thr
  p_kernel<<<NN / 256, 256, 0, stream>>>(RLpart, colpart, diag, pbuf, thrbuf);
  // 5) rank + max pass over rows of G2
  csls_gemm<1><<<(NN / BM) * NSTRIPE, 256, 0, stream>>>(Rb, Lb, nullptr, nullptr,
                                                        pbuf, thrbuf, cntp, mxp);
  // 6) reduce stripe parts -> outputs
  final_kernel<<<NN / 256, 256, 0, stream>>>(cntp, mxp, (float*)d_out);
}

// Round 7
// 1801.446 us; speedup vs baseline: 1.5771x; 1.0243x over previous
//
#include <hip/hip_runtime.h>
#include <hip/hip_bf16.h>
#include <stdint.h>

// Problem constants (fixed by setup_inputs)
#define NN 16384
#define DD 512
#define NSTRIPE 8     // column stripes
#define SCOLS 2048    // NN / NSTRIPE
#define BM 128        // block row tile
#define BN 128        // block col tile
#define BK 64         // k chunk staged in LDS
#define NTILES 16     // SCOLS / BN
#define NEG_INF (-3.0e38f)

// R7: XCD-locality swizzle. blk -> xcd=blk&7 (dispatch round-robin), t=blk>>3;
// rowtile = xcd*16 + (t&15), stripe = t>>4. Each XCD works a fixed 2 MB A-band
// + 2 MB B-stripe phase -> working set ~4 MB = XCD L2 -> kills the ~34x HBM
// re-fetch (R6 FETCH 1.06e6 KB) and the HBM-latency vmcnt(0) drains.

typedef unsigned short u16;
typedef _Float16 f16;
typedef __attribute__((ext_vector_type(8))) __bf16 bf16x8;   // MFMA A/B operand
typedef __attribute__((ext_vector_type(8))) short sh8;       // 16B vector
typedef __attribute__((ext_vector_type(8))) _Float16 f16x8;  // 16B of fp16
typedef __attribute__((ext_vector_type(4))) float f32x4;     // MFMA C/D

__device__ __forceinline__ u16 f2bf(float f) {  // RNE fp32->bf16
  uint32_t x = __float_as_uint(f);
  x += 0x7fffu + ((x >> 16) & 1u);
  return (u16)(x >> 16);
}
__device__ __forceinline__ float bf2f(u16 u) {
  return __uint_as_float(((uint32_t)u) << 16);
}

// async global->LDS, 16B per lane; lds base wave-uniform.
__device__ __forceinline__ void gload_lds16(const u16* g, u16* lds) {
  __builtin_amdgcn_global_load_lds(
      (const __attribute__((address_space(1))) uint32_t*)g,
      (__attribute__((address_space(3))) uint32_t*)lds,
      16, 0, 0);
}

// Insert v into descending-sorted 10-element register array.
__device__ __forceinline__ void ins10(float t[10], float v) {
  #pragma unroll
  for (int j = 0; j < 10; ++j) {
    float hi = fmaxf(t[j], v);
    v = fminf(t[j], v);
    t[j] = hi;
  }
}

__global__ __launch_bounds__(256) void cast_kernel(const float* __restrict__ src,
                                                   u16* __restrict__ dst) {
  int i = (blockIdx.x * 256 + threadIdx.x) * 8;
  const float4* s4 = reinterpret_cast<const float4*>(src + i);
  float4 a = s4[0], b = s4[1];
  sh8 o;
  o[0] = (short)f2bf(a.x); o[1] = (short)f2bf(a.y);
  o[2] = (short)f2bf(a.z); o[3] = (short)f2bf(a.w);
  o[4] = (short)f2bf(b.x); o[5] = (short)f2bf(b.y);
  o[6] = (short)f2bf(b.z); o[7] = (short)f2bf(b.w);
  *reinterpret_cast<sh8*>(dst + i) = o;
}

// diag[r] = <Lb_r, Rb_r> (bf16 inputs, fp32 accumulate) — one wave per row
__global__ __launch_bounds__(256) void diag_kernel(const u16* __restrict__ Lb,
                                                   const u16* __restrict__ Rb,
                                                   float* __restrict__ diag) {
  int r = blockIdx.x * 4 + (threadIdx.x >> 6);
  int lane = threadIdx.x & 63;
  sh8 a = *reinterpret_cast<const sh8*>(Lb + (size_t)r * DD + lane * 8);
  sh8 b = *reinterpret_cast<const sh8*>(Rb + (size_t)r * DD + lane * 8);
  float s = 0.f;
  #pragma unroll
  for (int j = 0; j < 8; ++j) s += bf2f((u16)a[j]) * bf2f((u16)b[j]);
  #pragma unroll
  for (int off = 32; off > 0; off >>= 1) s += __shfl_down(s, off);
  if (lane == 0) diag[r] = s;
}

// Fused GEMM + consumer over G2 = A*B^T (A=R, B=L).
// MODE 0: per-ROW top-10 (RL) -> row_part[N][8][10]  AND
//         per-COLUMN top-10 partials (LR) -> col_part[rowtile][N][10]
// MODE 1: per-row count(2v - p[col] > thr[row]) and max -> cnt/mx parts
template <int MODE>
__global__ __launch_bounds__(256) void csls_gemm(
    const u16* __restrict__ A, const u16* __restrict__ B,
    float* __restrict__ row_part, float* __restrict__ col_part,
    const float* __restrict__ p, const float* __restrict__ thr,
    int* __restrict__ cnt_out, float* __restrict__ mx_out) {
  // 17408 u16 = 34816 B: staging 2*8192 u16; MODE-0 fp16 C-view 128*136 f16.
  __shared__ __align__(16) u16 smem[17408];
  u16* sA = smem;            // [128][64] unpadded
  u16* sB = smem + 8192;     // [128][64] unpadded

  // --- R7 XCD-locality swizzle ---
  const int xcd = blockIdx.x & 7;
  const int t = blockIdx.x >> 3;
  const int rowtile = xcd * 16 + (t & 15);  // fixed 16-rowtile band per XCD
  const int stripe = t >> 4;                // B-stripe phase (16 blocks each)
  const int rowbase = rowtile * BM;
  const int sbase = stripe * SCOLS;

  const int tid = threadIdx.x;
  const int w = tid >> 6;
  const int lane = tid & 63;
  const int quad = lane >> 4;
  const int l16 = lane & 15;
  const int wr = (w >> 1) * 64;  // wave quadrant rows
  const int wc = (w & 1) * 64;   // wave quadrant cols

  // staging-lane decomposition: 8 rows x 8 granules per DMA instr, straight order
  const int lrow8 = lane >> 3;   // row within 8-row group
  const int gran = lane & 7;     // 16B granule this lane fetches

  float tk[10];      // MODE 0: running top-10 of (row = tid>>1, col-half = tid&1)
  int cnt[16];       // MODE 1: per (fr,reg) row this lane holds
  float mx[16];
  float thrv[16];
  if constexpr (MODE == 0) {
    #pragma unroll
    for (int j = 0; j < 10; ++j) tk[j] = NEG_INF;
  } else {
    #pragma unroll
    for (int i = 0; i < 16; ++i) {
      cnt[i] = 0;
      mx[i] = NEG_INF;
      int fr = i >> 2, reg = i & 3;
      thrv[i] = thr[rowbase + wr + 16 * fr + quad * 4 + reg];
    }
  }

  for (int tile = 0; tile < NTILES; ++tile) {
    const int colbase = sbase + tile * BN;
    f32x4 acc[4][4];
    #pragma unroll
    for (int a_ = 0; a_ < 4; ++a_)
      #pragma unroll
      for (int b_ = 0; b_ < 4; ++b_) acc[a_][b_] = (f32x4){0.f, 0.f, 0.f, 0.f};

    float pv[4];
    if constexpr (MODE == 1) {
      #pragma unroll
      for (int fc = 0; fc < 4; ++fc) pv[fc] = p[colbase + wc + 16 * fc + l16];
    }

    for (int kk = 0; kk < DD; kk += BK) {
      #pragma unroll
      for (int it = 0; it < 4; ++it) {
        int rgrp = w * 32 + it * 8;
        gload_lds16(A + (size_t)(rowbase + rgrp + lrow8) * DD + kk + gran * 8, sA + rgrp * 64);
        gload_lds16(B + (size_t)(colbase + rgrp + lrow8) * DD + kk + gran * 8, sB + rgrp * 64);
      }
      __syncthreads();
      #pragma unroll
      for (int ks = 0; ks < BK; ks += 32) {
        bf16x8 af[4], bfr[4];
        #pragma unroll
        for (int f = 0; f < 4; ++f) {
          int ra = wr + 16 * f + l16;
          int rb = wc + 16 * f + l16;
          af[f]  = *reinterpret_cast<const bf16x8*>(sA + ra * 64 + ks + quad * 8);
          bfr[f] = *reinterpret_cast<const bf16x8*>(sB + rb * 64 + ks + quad * 8);
        }
        #pragma unroll
        for (int fr = 0; fr < 4; ++fr)
          #pragma unroll
          for (int fc = 0; fc < 4; ++fc)
            acc[fr][fc] = __builtin_amdgcn_mfma_f32_16x16x32_bf16(af[fr], bfr[fc], acc[fr][fc], 0, 0, 0);
      }
      __syncthreads();
    }

    if constexpr (MODE == 0) {
      // single fp16 dump [128][136], conflict-free scans
      f16* hC = reinterpret_cast<f16*>(smem);
      #pragma unroll
      for (int fr = 0; fr < 4; ++fr)
        #pragma unroll
        for (int fc = 0; fc < 4; ++fc)
          #pragma unroll
          for (int reg = 0; reg < 4; ++reg)
            hC[(wr + 16 * fr + quad * 4 + reg) * 136 + wc + 16 * fc + l16] =
                (f16)acc[fr][fc][reg];
      __syncthreads();
      // row scan: thread owns (row = tid>>1, col-half = tid&1); 8x f16x8 reads.
      {
        const int row = tid >> 1, hf = tid & 1;
        const f16* q = hC + row * 136 + hf * 64;
        #pragma unroll
        for (int c8 = 0; c8 < 8; ++c8) {
          f16x8 v8 = *reinterpret_cast<const f16x8*>(q + c8 * 8);
          #pragma unroll
          for (int j = 0; j < 8; ++j) {
            float v = (float)v8[j];
            if (v > tk[9]) ins10(tk, v);
          }
        }
      }
      // col scan: thread owns (col = tid&127, row-half = tid>>7); 64 b16 reads.
      float ck[10];
      #pragma unroll
      for (int j = 0; j < 10; ++j) ck[j] = NEG_INF;
      {
        const int c = tid & 127, rh = tid >> 7;
        #pragma unroll 8
        for (int i = 0; i < 64; ++i) {
          float v = (float)hC[(rh * 64 + i) * 136 + c];
          if (v > ck[9]) ins10(ck, v);
        }
      }
      __syncthreads();
      // flush this tile's column partials: sP[col][half][10], stride 21 (pad)
      float* sP = reinterpret_cast<float*>(smem);  // 128*21*4 = 10752 B
      {
        const int c = tid & 127, rh = tid >> 7;
        #pragma unroll
        for (int j = 0; j < 10; ++j) sP[c * 21 + rh * 10 + j] = ck[j];
      }
      __syncthreads();
      if (tid < 128) {
        float best[10];
        #pragma unroll
        for (int j = 0; j < 10; ++j) best[j] = NEG_INF;
        #pragma unroll
        for (int j = 0; j < 20; ++j) {
          float v = sP[tid * 21 + j];
          if (v > best[9]) ins10(best, v);
        }
        size_t base = ((size_t)rowtile * NN + colbase + tid) * 10;
        #pragma unroll
        for (int j = 0; j < 10; ++j) col_part[base + j] = best[j];
      }
      __syncthreads();
    } else {
      // Register-direct consume: csls = 2*v - p[col]; count > thr[row]; max.
      #pragma unroll
      for (int fc = 0; fc < 4; ++fc)
        #pragma unroll
        for (int fr = 0; fr < 4; ++fr)
          #pragma unroll
          for (int reg = 0; reg < 4; ++reg) {
            float t2 = 2.f * acc[fr][fc][reg] - pv[fc];
            int idx = fr * 4 + reg;
            cnt[idx] += (t2 > thrv[idx]) ? 1 : 0;
            mx[idx] = fmaxf(mx[idx], t2);
          }
    }
  }

  if constexpr (MODE == 0) {
    // Merge the 2 col-half partials per row (hoisted out of the tile loop).
    float* sM = reinterpret_cast<float*>(smem);  // [128][21]
    #pragma unroll
    for (int j = 0; j < 10; ++j)
      sM[(tid >> 1) * 21 + (tid & 1) * 10 + j] = tk[j];
    __syncthreads();
    if (tid < 128) {
      float best[10];
      #pragma unroll
      for (int j = 0; j < 10; ++j) best[j] = NEG_INF;
      #pragma unroll
      for (int j = 0; j < 20; ++j) {
        float v = sM[tid * 21 + j];
        if (v > best[9]) ins10(best, v);
      }
      #pragma unroll
      for (int j = 0; j < 10; ++j)
        row_part[(size_t)(rowbase + tid) * 80 + stripe * 10 + j] = best[j];
    }
  } else {
    // Rows covered by TWO waves (column halves): shuffle-reduce, LDS-combine.
    float* sMx = reinterpret_cast<float*>(smem);        // [4][64] floats
    int*   sCn = reinterpret_cast<int*>(smem) + 256;    // [4][64] ints
    #pragma unroll
    for (int idx = 0; idx < 16; ++idx) {
      int c = cnt[idx];
      float m = mx[idx];
      #pragma unroll
      for (int off = 1; off < 16; off <<= 1) {
        c += __shfl_xor(c, off);
        m = fmaxf(m, __shfl_xor(m, off));
      }
      if (l16 == 0) {
        int fr = idx >> 2, reg = idx & 3;
        int rloc = 16 * fr + quad * 4 + reg;
        sMx[w * 64 + rloc] = m;
        sCn[w * 64 + rloc] = c;
      }
    }
    __syncthreads();
    if (tid < 128) {
      int half = tid >> 6;
      int rloc = tid & 63;
      int c = sCn[(half * 2) * 64 + rloc] + sCn[(half * 2 + 1) * 64 + rloc];
      float m = fmaxf(sMx[(half * 2) * 64 + rloc], sMx[(half * 2 + 1) * 64 + rloc]);
      cnt_out[(rowbase + tid) * 8 + stripe] = c;
      mx_out[(rowbase + tid) * 8 + stripe] = m;
    }
  }
}

// Per entity l: RL[l] = mean top-10 of row_part[l][80]; LR[l] = mean top-10 of
// col_part[t][l][10] over t=0..127. p = LR+RL; thr = 2*diag - p.
__global__ __launch_bounds__(256) void p_kernel(const float* __restrict__ RLp,
                                                const float* __restrict__ colp,
                                                const float* __restrict__ diag,
                                                float* __restrict__ pout,
                                                float* __restrict__ throut) {
  int l = blockIdx.x * 256 + threadIdx.x;
  float b1[10], b2[10];
  #pragma unroll
  for (int j = 0; j < 10; ++j) { b1[j] = NEG_INF; b2[j] = NEG_INF; }
  for (int s = 0; s < 8; ++s) {
    for (int j = 0; j < 10; ++j) {   // stripe partials sorted desc -> early break
      float v = RLp[(size_t)l * 80 + s * 10 + j];
      if (v > b1[9]) ins10(b1, v); else break;
    }
  }
  for (int t = 0; t < 128; ++t) {
    for (int j = 0; j < 10; ++j) {   // rowtile partials sorted desc -> early break
      float v = colp[((size_t)t * NN + l) * 10 + j];
      if (v > b2[9]) ins10(b2, v); else break;
    }
  }
  float s1 = 0.f, s2 = 0.f;
  #pragma unroll
  for (int j = 0; j < 10; ++j) { s1 += b1[j]; s2 += b2[j]; }
  float pv = (s1 + s2) * 0.1f;
  pout[l] = pv;
  throut[l] = 2.f * diag[l] - pv;
}

__global__ __launch_bounds__(256) void final_kernel(const int* __restrict__ cnt,
                                                    const float* __restrict__ mx,
                                                    float* __restrict__ out) {
  int r = blockIdx.x * 256 + threadIdx.x;
  int c = 0;
  float m = NEG_INF;
  #pragma unroll
  for (int s = 0; s < 8; ++s) {
    c += cnt[r * 8 + s];
    m = fmaxf(m, mx[r * 8 + s]);
  }
  out[r] = (float)c;   // rank of the diagonal element (count strictly greater)
  out[NN + r] = m;     // top-1 csls value
}

extern "C" void kernel_launch(void* const* d_in, const int* in_sizes, int n_in,
                              void* d_out, int out_size, void* d_ws, size_t ws_size,
                              hipStream_t stream) {
  const float* L = (const float*)d_in[0];
  const float* R = (const float*)d_in[1];
  char* ws = (char*)d_ws;

  u16* Lb = (u16*)ws;                                   // 16 MB
  u16* Rb = (u16*)(ws + (16ull << 20));                 // 16 MB
  size_t off = 32ull << 20;
  float* colpart = (float*)(ws + off); off += (size_t)NN * 128 * 10 * 4;  // 80 MB
  float* RLpart  = (float*)(ws + off); off += (size_t)NN * 80 * 4;        // 5.24 MB
  float* diag    = (float*)(ws + off); off += (size_t)NN * 4;
  float* pbuf    = (float*)(ws + off); off += (size_t)NN * 4;
  float* thrbuf  = (float*)(ws + off); off += (size_t)NN * 4;
  int*   cntp    = (int*)(ws + off);   off += (size_t)NN * 8 * 4;
  float* mxp     = (float*)(ws + off); off += (size_t)NN * 8 * 4;  // ~119 MB total

  // 1) fp32 -> bf16 casts
  cast_kernel<<<(NN * DD / (256 * 8)), 256, 0, stream>>>(L, Lb);
  cast_kernel<<<(NN * DD / (256 * 8)), 256, 0, stream>>>(R, Rb);
  // 2) diagonal sim values
  diag_kernel<<<NN / 4, 256, 0, stream>>>(Lb, Rb, diag);
  // 3) fused pass over G2 = R*L^T: row top-10 (RL) + col top-10 partials (LR)
  csls_gemm<0><<<(NN / BM) * NSTRIPE, 256, 0, stream>>>(Rb, Lb, RLpart, colpart,
                                                        nullptr, nullptr, nullptr, nullptr);
  // 4) merge partials -> p, thr
  p_kernel<<<NN / 256, 256, 0, stream>>>(RLpart, colpart, diag, pbuf, thrbuf);
  // 5) rank + max pass over rows of G2
  csls_gemm<1><<<(NN / BM) * NSTRIPE, 256, 0, stream>>>(Rb, Lb, nullptr, nullptr,
                                                        pbuf, thrbuf, cntp, mxp);
  // 6) reduce stripe parts -> outputs
  final_kernel<<<NN / 256, 256, 0, stream>>>(cntp, mxp, (float*)d_out);
}

// Round 8
// 1707.478 us; speedup vs baseline: 1.6639x; 1.0550x over previous
//
#include <hip/hip_runtime.h>
#include <hip/hip_bf16.h>
#include <stdint.h>

// Problem constants (fixed by setup_inputs)
#define NN 16384
#define DD 512
#define BM 128
#define BN 128
#define BK 64
#define NCT 128       // column tiles (= NN/BN) = per-row partial segments
#define NEG_INF (-3.0e38f)

// R8: one 128x128 output tile per block (m97-faithful), grid 16384 = 64
// blocks/CU. Per-block overhead amortized over one K=512 run; inter-block
// overlap hides barrier drains. XCD swizzle kept (R7: FETCH -14x, verified).

typedef unsigned short u16;
typedef _Float16 f16;
typedef __attribute__((ext_vector_type(8))) __bf16 bf16x8;   // MFMA A/B operand
typedef __attribute__((ext_vector_type(8))) short sh8;       // 16B vector
typedef __attribute__((ext_vector_type(8))) _Float16 f16x8;  // 16B of fp16
typedef __attribute__((ext_vector_type(4))) float f32x4;     // MFMA C/D

__device__ __forceinline__ u16 f2bf(float f) {  // RNE fp32->bf16
  uint32_t x = __float_as_uint(f);
  x += 0x7fffu + ((x >> 16) & 1u);
  return (u16)(x >> 16);
}
__device__ __forceinline__ float bf2f(u16 u) {
  return __uint_as_float(((uint32_t)u) << 16);
}

// async global->LDS, 16B per lane; lds base wave-uniform.
__device__ __forceinline__ void gload_lds16(const u16* g, u16* lds) {
  __builtin_amdgcn_global_load_lds(
      (const __attribute__((address_space(1))) uint32_t*)g,
      (__attribute__((address_space(3))) uint32_t*)lds,
      16, 0, 0);
}

// Insert v into descending-sorted 10-element register array.
__device__ __forceinline__ void ins10(float t[10], float v) {
  #pragma unroll
  for (int j = 0; j < 10; ++j) {
    float hi = fmaxf(t[j], v);
    v = fminf(t[j], v);
    t[j] = hi;
  }
}

__global__ __launch_bounds__(256) void cast_kernel(const float* __restrict__ src,
                                                   u16* __restrict__ dst) {
  int i = (blockIdx.x * 256 + threadIdx.x) * 8;
  const float4* s4 = reinterpret_cast<const float4*>(src + i);
  float4 a = s4[0], b = s4[1];
  sh8 o;
  o[0] = (short)f2bf(a.x); o[1] = (short)f2bf(a.y);
  o[2] = (short)f2bf(a.z); o[3] = (short)f2bf(a.w);
  o[4] = (short)f2bf(b.x); o[5] = (short)f2bf(b.y);
  o[6] = (short)f2bf(b.z); o[7] = (short)f2bf(b.w);
  *reinterpret_cast<sh8*>(dst + i) = o;
}

// diag[r] = <Lb_r, Rb_r> — one wave per row
__global__ __launch_bounds__(256) void diag_kernel(const u16* __restrict__ Lb,
                                                   const u16* __restrict__ Rb,
                                                   float* __restrict__ diag) {
  int r = blockIdx.x * 4 + (threadIdx.x >> 6);
  int lane = threadIdx.x & 63;
  sh8 a = *reinterpret_cast<const sh8*>(Lb + (size_t)r * DD + lane * 8);
  sh8 b = *reinterpret_cast<const sh8*>(Rb + (size_t)r * DD + lane * 8);
  float s = 0.f;
  #pragma unroll
  for (int j = 0; j < 8; ++j) s += bf2f((u16)a[j]) * bf2f((u16)b[j]);
  #pragma unroll
  for (int off = 32; off > 0; off >>= 1) s += __shfl_down(s, off);
  if (lane == 0) diag[r] = s;
}

// Shared block-coordinate decode + K-loop body (single 128x128 tile, K=512).
// xcd = blk&7 -> fixed 16-rowtile A-band per XCD; coltile sweeps slowly.
#define DECODE_TILE()                                   \
  const int xcd = blockIdx.x & 7;                       \
  const int idx = blockIdx.x >> 3;                      \
  const int rowtile = xcd * 16 + (idx & 15);            \
  const int coltile = idx >> 4;                         \
  const int rowbase = rowtile * BM;                     \
  const int colbase = coltile * BN;                     \
  const int tid = threadIdx.x;                          \
  const int w = tid >> 6;                               \
  const int lane = tid & 63;                            \
  const int quad = lane >> 4;                           \
  const int l16 = lane & 15;                            \
  const int wr = (w >> 1) * 64;                         \
  const int wc = (w & 1) * 64;                          \
  const int lrow8 = lane >> 3;                          \
  const int gran = lane & 7;

#define GEMM_K_LOOP(sA, sB)                                                     \
  f32x4 acc[4][4];                                                              \
  _Pragma("unroll")                                                             \
  for (int a_ = 0; a_ < 4; ++a_)                                                \
    _Pragma("unroll")                                                           \
    for (int b_ = 0; b_ < 4; ++b_) acc[a_][b_] = (f32x4){0.f, 0.f, 0.f, 0.f};   \
  {                                                                             \
    const u16* gA = A + (size_t)(rowbase + w * 32 + lrow8) * DD + gran * 8;     \
    const u16* gB = B + (size_t)(colbase + w * 32 + lrow8) * DD + gran * 8;     \
    for (int kk = 0; kk < DD; kk += BK) {                                       \
      _Pragma("unroll")                                                         \
      for (int it = 0; it < 4; ++it) {                                          \
        gload_lds16(gA + (size_t)it * 8 * DD + kk, sA + (w * 32 + it * 8) * 64);\
        gload_lds16(gB + (size_t)it * 8 * DD + kk, sB + (w * 32 + it * 8) * 64);\
      }                                                                         \
      __syncthreads();                                                          \
      _Pragma("unroll")                                                         \
      for (int ks = 0; ks < BK; ks += 32) {                                     \
        bf16x8 af[4], bfr[4];                                                   \
        _Pragma("unroll")                                                       \
        for (int f = 0; f < 4; ++f) {                                           \
          af[f]  = *reinterpret_cast<const bf16x8*>(sA + (wr + 16 * f + l16) * 64 + ks + quad * 8); \
          bfr[f] = *reinterpret_cast<const bf16x8*>(sB + (wc + 16 * f + l16) * 64 + ks + quad * 8); \
        }                                                                       \
        _Pragma("unroll")                                                       \
        for (int fr = 0; fr < 4; ++fr)                                          \
          _Pragma("unroll")                                                     \
          for (int fc = 0; fc < 4; ++fc)                                        \
            acc[fr][fc] = __builtin_amdgcn_mfma_f32_16x16x32_bf16(af[fr], bfr[fc], acc[fr][fc], 0, 0, 0); \
      }                                                                         \
      __syncthreads();                                                          \
    }                                                                           \
  }

// Pass 1: G2 tile + row top-10 partials (RL) + col top-10 partials (LR).
// rowp[row][coltile][10] f16 ; colp[col][rowtile][10] f16 (sorted desc).
__global__ __launch_bounds__(256) void gemm_topk(const u16* __restrict__ A,
                                                 const u16* __restrict__ B,
                                                 f16* __restrict__ rowp,
                                                 f16* __restrict__ colp) {
  __shared__ __align__(16) u16 smem[17408];  // 34816 B (epi fp16 view 128x136)
  u16* sA = smem;
  u16* sB = smem + 8192;
  DECODE_TILE()
  GEMM_K_LOOP(sA, sB)

  // fp16 dump [128][136]
  f16* hC = reinterpret_cast<f16*>(smem);
  #pragma unroll
  for (int fr = 0; fr < 4; ++fr)
    #pragma unroll
    for (int fc = 0; fc < 4; ++fc)
      #pragma unroll
      for (int reg = 0; reg < 4; ++reg)
        hC[(wr + 16 * fr + quad * 4 + reg) * 136 + wc + 16 * fc + l16] =
            (f16)acc[fr][fc][reg];
  __syncthreads();
  // row scan: thread owns (row = tid>>1, col-half = tid&1)
  float tk[10];
  #pragma unroll
  for (int j = 0; j < 10; ++j) tk[j] = NEG_INF;
  {
    const f16* q = hC + (tid >> 1) * 136 + (tid & 1) * 64;
    #pragma unroll
    for (int c8 = 0; c8 < 8; ++c8) {
      f16x8 v8 = *reinterpret_cast<const f16x8*>(q + c8 * 8);
      #pragma unroll
      for (int j = 0; j < 8; ++j) {
        float v = (float)v8[j];
        if (v > tk[9]) ins10(tk, v);
      }
    }
  }
  // col scan: thread owns (col = tid&127, row-half = tid>>7)
  float ck[10];
  #pragma unroll
  for (int j = 0; j < 10; ++j) ck[j] = NEG_INF;
  {
    const int c = tid & 127, rh = tid >> 7;
    #pragma unroll 8
    for (int i = 0; i < 64; ++i) {
      float v = (float)hC[(rh * 64 + i) * 136 + c];
      if (v > ck[9]) ins10(ck, v);
    }
  }
  __syncthreads();
  // merge col halves -> colp
  float* sP = reinterpret_cast<float*>(smem);  // [128][21]
  {
    const int c = tid & 127, rh = tid >> 7;
    #pragma unroll
    for (int j = 0; j < 10; ++j) sP[c * 21 + rh * 10 + j] = ck[j];
  }
  __syncthreads();
  if (tid < 128) {
    float best[10];
    #pragma unroll
    for (int j = 0; j < 10; ++j) best[j] = NEG_INF;
    #pragma unroll
    for (int j = 0; j < 20; ++j) {
      float v = sP[tid * 21 + j];
      if (v > best[9]) ins10(best, v);
    }
    f16* o = colp + ((size_t)(colbase + tid) * NCT + rowtile) * 10;
    #pragma unroll
    for (int j = 0; j < 10; ++j) o[j] = (f16)best[j];
  }
  __syncthreads();
  // merge row halves -> rowp
  float* sM = reinterpret_cast<float*>(smem);  // [128][21]
  #pragma unroll
  for (int j = 0; j < 10; ++j)
    sM[(tid >> 1) * 21 + (tid & 1) * 10 + j] = tk[j];
  __syncthreads();
  if (tid < 128) {
    float best[10];
    #pragma unroll
    for (int j = 0; j < 10; ++j) best[j] = NEG_INF;
    #pragma unroll
    for (int j = 0; j < 20; ++j) {
      float v = sM[tid * 21 + j];
      if (v > best[9]) ins10(best, v);
    }
    f16* o = rowp + ((size_t)(rowbase + tid) * NCT + coltile) * 10;
    #pragma unroll
    for (int j = 0; j < 10; ++j) o[j] = (f16)best[j];
  }
}

// Pass 2: G2 tile + count(2v - p[col] > thr[row]) and max(2v - p[col]).
__global__ __launch_bounds__(256) void gemm_rank(const u16* __restrict__ A,
                                                 const u16* __restrict__ B,
                                                 const float* __restrict__ p,
                                                 const float* __restrict__ thr,
                                                 int* __restrict__ cnt_out,
                                                 float* __restrict__ mx_out) {
  __shared__ __align__(16) u16 smem[16384];  // 32768 B
  u16* sA = smem;
  u16* sB = smem + 8192;
  DECODE_TILE()

  float thrv[16];
  #pragma unroll
  for (int i = 0; i < 16; ++i)
    thrv[i] = thr[rowbase + wr + 16 * (i >> 2) + quad * 4 + (i & 3)];
  float pv[4];
  #pragma unroll
  for (int fc = 0; fc < 4; ++fc) pv[fc] = p[colbase + wc + 16 * fc + l16];

  GEMM_K_LOOP(sA, sB)

  int cnt[16];
  float mx[16];
  #pragma unroll
  for (int i = 0; i < 16; ++i) { cnt[i] = 0; mx[i] = NEG_INF; }
  #pragma unroll
  for (int fc = 0; fc < 4; ++fc)
    #pragma unroll
    for (int fr = 0; fr < 4; ++fr)
      #pragma unroll
      for (int reg = 0; reg < 4; ++reg) {
        float t2 = 2.f * acc[fr][fc][reg] - pv[fc];
        int idx = fr * 4 + reg;
        cnt[idx] += (t2 > thrv[idx]) ? 1 : 0;
        mx[idx] = fmaxf(mx[idx], t2);
      }

  // reduce across 16 col-lanes, then combine the two col-half waves per row
  float* sMx = reinterpret_cast<float*>(smem);        // [4][64]
  int*   sCn = reinterpret_cast<int*>(smem) + 256;    // [4][64]
  #pragma unroll
  for (int idx = 0; idx < 16; ++idx) {
    int c = cnt[idx];
    float m = mx[idx];
    #pragma unroll
    for (int off = 1; off < 16; off <<= 1) {
      c += __shfl_xor(c, off);
      m = fmaxf(m, __shfl_xor(m, off));
    }
    if (l16 == 0) {
      int rloc = 16 * (idx >> 2) + quad * 4 + (idx & 3);
      sMx[w * 64 + rloc] = m;
      sCn[w * 64 + rloc] = c;
    }
  }
  __syncthreads();
  if (tid < 128) {
    int half = tid >> 6, rloc = tid & 63;
    int c = sCn[(half * 2) * 64 + rloc] + sCn[(half * 2 + 1) * 64 + rloc];
    float m = fmaxf(sMx[(half * 2) * 64 + rloc], sMx[(half * 2 + 1) * 64 + rloc]);
    cnt_out[(size_t)(rowbase + tid) * NCT + coltile] = c;
    mx_out[(size_t)(rowbase + tid) * NCT + coltile] = m;
  }
}

// p[l] = mean(top10 of rowp[l][*]) + mean(top10 of colp[l][*]); thr = 2*diag - p
__global__ __launch_bounds__(256) void p_kernel(const f16* __restrict__ rowp,
                                                const f16* __restrict__ colp,
                                                const float* __restrict__ diag,
                                                float* __restrict__ pout,
                                                float* __restrict__ throut) {
  int l = blockIdx.x * 256 + threadIdx.x;
  float b1[10], b2[10];
  #pragma unroll
  for (int j = 0; j < 10; ++j) { b1[j] = NEG_INF; b2[j] = NEG_INF; }
  for (int s = 0; s < NCT; ++s) {
    const f16* q1 = rowp + ((size_t)l * NCT + s) * 10;
    for (int j = 0; j < 10; ++j) {   // sorted desc -> early break
      float v = (float)q1[j];
      if (v > b1[9]) ins10(b1, v); else break;
    }
    const f16* q2 = colp + ((size_t)l * NCT + s) * 10;
    for (int j = 0; j < 10; ++j) {
      float v = (float)q2[j];
      if (v > b2[9]) ins10(b2, v); else break;
    }
  }
  float s1 = 0.f, s2 = 0.f;
  #pragma unroll
  for (int j = 0; j < 10; ++j) { s1 += b1[j]; s2 += b2[j]; }
  float pv = (s1 + s2) * 0.1f;
  pout[l] = pv;
  throut[l] = 2.f * diag[l] - pv;
}

__global__ __launch_bounds__(256) void final_kernel(const int* __restrict__ cnt,
                                                    const float* __restrict__ mx,
                                                    float* __restrict__ out) {
  int r = blockIdx.x * 256 + threadIdx.x;
  int c = 0;
  float m = NEG_INF;
  for (int s = 0; s < NCT; ++s) {
    c += cnt[(size_t)r * NCT + s];
    m = fmaxf(m, mx[(size_t)r * NCT + s]);
  }
  out[r] = (float)c;   // rank of the diagonal element (count strictly greater)
  out[NN + r] = m;     // top-1 csls value
}

extern "C" void kernel_launch(void* const* d_in, const int* in_sizes, int n_in,
                              void* d_out, int out_size, void* d_ws, size_t ws_size,
                              hipStream_t stream) {
  const float* L = (const float*)d_in[0];
  const float* R = (const float*)d_in[1];
  char* ws = (char*)d_ws;

  const size_t PARTB = (size_t)NN * NCT * 10 * 2;       // 41.94 MB per partial
  u16* Lb   = (u16*)ws;                                 // 16 MB
  u16* Rb   = (u16*)(ws + (16ull << 20));               // 16 MB
  f16* rowp = (f16*)(ws + (32ull << 20));               // RL partials
  f16* colp = (f16*)(ws + (32ull << 20) + PARTB);       // LR partials
  size_t off = (32ull << 20) + 2 * PARTB;
  float* diag   = (float*)(ws + off); off += (size_t)NN * 4;
  float* pbuf   = (float*)(ws + off); off += (size_t)NN * 4;
  float* thrbuf = (float*)(ws + off); off += (size_t)NN * 4;   // ~112 MB total
  // cnt/mx alias colp's region (colp fully consumed by p_kernel first)
  int*   cntp = (int*)colp;                             // 8.4 MB
  float* mxp  = (float*)((char*)colp + (20ull << 20));  // 8.4 MB

  // 1) fp32 -> bf16 casts
  cast_kernel<<<(NN * DD / (256 * 8)), 256, 0, stream>>>(L, Lb);
  cast_kernel<<<(NN * DD / (256 * 8)), 256, 0, stream>>>(R, Rb);
  // 2) diagonal sim values
  diag_kernel<<<NN / 4, 256, 0, stream>>>(Lb, Rb, diag);
  // 3) pass 1 over G2 = R*L^T: row top-10 (RL) + col top-10 (LR) partials
  gemm_topk<<<(NN / BM) * (NN / BN), 256, 0, stream>>>(Rb, Lb, rowp, colp);
  // 4) merge partials -> p, thr
  p_kernel<<<NN / 256, 256, 0, stream>>>(rowp, colp, diag, pbuf, thrbuf);
  // 5) pass 2: rank + max
  gemm_rank<<<(NN / BM) * (NN / BN), 256, 0, stream>>>(Rb, Lb, pbuf, thrbuf, cntp, mxp);
  // 6) reduce segments -> outputs
  final_kernel<<<NN / 256, 256, 0, stream>>>(cntp, mxp, (float*)d_out);
}